// Round 8
// baseline (378.063 us; speedup 1.0000x reference)
//
#include <hip/hip_runtime.h>

// Spatially varying anisotropic 2D elastic wave sim, 384x384, 192 steps.
// Round 7: R6 geometry (256 blocks=1/CU, 256 thr, 48x48 staging, K=12, 16
// launches, packed v2f LDS + pk-math) with two stall-removals:
//  - raw "s_waitcnt lgkmcnt(0); s_barrier" instead of __syncthreads: the
//    barrier no longer drains vmcnt, so frame stores / prologue loads never
//    block the step loop (all cross-thread traffic is LDS-only => correct)
//  - padded LDS sb[2][50][53], data at [1..48][1..48], zeroed pad ring:
//    halo reads are static unclamped offsets -> ds_read2_b64 merging
//    (16 -> ~10 read insts, 9 -> ~6 write insts), clamp VALU gone.
//    Row stride 53 keeps tx-groups on distinct banks (12*106 % 32 = 24).

typedef float v2f __attribute__((ext_vector_type(2)));

#define NXg 384
#define NYg 384
#define NPT (NXg * NYg)
#define NFRAMES 48

#define OWN 24
#define HALO 12
#define TS 48
#define KSTEPS 12
#define NLAUNCH 16

#define SROW 50       // padded rows
#define SCOL 53       // padded cols (bank-stagger: 53*2 dwords/row)

#define H_   1e-4
#define DT_  5e-9
#define RHO_ 1610.0

#define B11_LO 5e10f
#define B11_HI 2.5e11f
#define B22_LO 5e9f
#define B22_HI 5e10f
#define B12_LO 5e9f
#define B12_HI 5e10f
#define B16_LO 0.0f
#define B16_HI 6e10f
#define B26_LO 0.0f
#define B26_HI 2e10f
#define B66_LO 5e9f
#define B66_HI 3e10f

static __device__ __constant__ float kScale  = (float)(DT_ * DT_ / (H_ * H_) / RHO_);
static __device__ __constant__ float kSrcScl = (float)(DT_ * DT_ / RHO_);

__device__ __forceinline__ float clipf(float v, float lo, float hi) {
    return fminf(fmaxf(v, lo), hi);
}
__device__ __forceinline__ v2f vfma(v2f a, v2f b, v2f c) {
    return __builtin_elementwise_fma(a, b, c);
}
__device__ __forceinline__ v2f vbc(float s) { v2f r; r[0] = s; r[1] = s; return r; }

// barrier that only waits LDS (no vmcnt drain); memory clobber pins ordering
#define LDS_BARRIER() asm volatile("s_waitcnt lgkmcnt(0)\n\ts_barrier" ::: "memory")

// ws float layout:
// [0..7NPT): coeff planes A11,A22,A12p66,A16,A26,A66,GS (pre-scaled)
// [7NPT..11NPT):  state set0 (cur v2f[NPT], old v2f[NPT])
// [11NPT..15NPT): state set1

__global__ __launch_bounds__(256)
void setup_kernel(const float* __restrict__ lc11, const float* __restrict__ lc12,
                  const float* __restrict__ lc16, const float* __restrict__ lc22,
                  const float* __restrict__ lc26, const float* __restrict__ lc66,
                  const float* __restrict__ gauss, float* __restrict__ ws) {
    int i = blockIdx.x * blockDim.x + threadIdx.x;
    if (i >= NPT) return;
    float C11 = clipf(expf(lc11[i]), B11_LO, B11_HI);
    float C12 = clipf(expf(lc12[i]), B12_LO, B12_HI);
    float C16 = clipf(expf(lc16[i]), B16_LO, B16_HI);
    float C22 = clipf(expf(lc22[i]), B22_LO, B22_HI);
    float C26 = clipf(expf(lc26[i]), B26_LO, B26_HI);
    float C66 = clipf(expf(lc66[i]), B66_LO, B66_HI);
    float s = kScale;
    ws[0 * NPT + i] = C11 * s;
    ws[1 * NPT + i] = C22 * s;
    ws[2 * NPT + i] = (C12 + C66) * s;
    ws[3 * NPT + i] = C16 * s;
    ws[4 * NPT + i] = C26 * s;
    ws[5 * NPT + i] = C66 * s;
    ws[6 * NPT + i] = gauss[i] * kSrcScl;
    v2f* c0 = (v2f*)(ws + 7 * (size_t)NPT);
    v2f* o0 = c0 + NPT;
    c0[i] = vbc(0.0f);
    o0[i] = vbc(0.0f);
}

__global__ __launch_bounds__(256, 1)
void fused_kernel(const float* __restrict__ ws, const float* __restrict__ sig,
                  const v2f* __restrict__ inCur, const v2f* __restrict__ inOld,
                  v2f* __restrict__ outCur, v2f* __restrict__ outOld,
                  float* __restrict__ out, int L) {
    __shared__ v2f sb[2][SROW][SCOL];

    const int tid = threadIdx.x;
    const int tx = tid >> 4;
    const int ty = tid & 15;
    const int r1 = 3 * tx + 1;        // pad-coord first data row
    const int c1 = 3 * ty + 1;        // pad-coord first data col
    const int gx0 = blockIdx.y * OWN - HALO;
    const int gy0 = blockIdx.x * OWN - HALO;

    v2f cur[9], old_[9];
    float a11[9], a22[9], a12p66[9], a16[9], a26[9], a66[9], gs[9];
    int gidx[9];

#pragma unroll
    for (int i = 0; i < 3; ++i) {
#pragma unroll
        for (int j = 0; j < 3; ++j) {
            int p = i * 3 + j;
            int gx = gx0 + 3 * tx + i;
            int gy = gy0 + 3 * ty + j;
            bool d = (unsigned)gx < (unsigned)NXg && (unsigned)gy < (unsigned)NYg;
            int g = d ? gx * NYg + gy : 0;
            gidx[p] = g;
            cur[p]  = d ? inCur[g] : vbc(0.0f);
            old_[p] = d ? inOld[g] : vbc(0.0f);
            // out-of-domain -> zero coeffs => point stays exactly 0
            a11[p]    = d ? ws[0 * NPT + g] : 0.0f;
            a22[p]    = d ? ws[1 * NPT + g] : 0.0f;
            a12p66[p] = d ? ws[2 * NPT + g] : 0.0f;
            a16[p]    = d ? ws[3 * NPT + g] : 0.0f;
            a26[p]    = d ? ws[4 * NPT + g] : 0.0f;
            a66[p]    = d ? ws[5 * NPT + g] : 0.0f;
            gs[p]     = d ? ws[6 * NPT + g] : 0.0f;
        }
    }

    const bool owned = (tx >= 4) && (tx < 12) && (ty >= 4) && (ty < 12);
    const int t0 = L * KSTEPS;

    // zero the pad ring of BOTH buffers (reads touch rows/cols 0 and 49)
    for (int k = tid; k < SROW * SCOL; k += 256) {
        int r = k / SCOL, c = k % SCOL;
        if (r == 0 || r == SROW - 1 || c == 0 || c >= TS + 1) {
            sb[0][r][c] = vbc(0.0f);
            sb[1][r][c] = vbc(0.0f);
        }
    }
    // publish initial values into buffer 0
#pragma unroll
    for (int i = 0; i < 3; ++i)
#pragma unroll
        for (int j = 0; j < 3; ++j)
            sb[0][r1 + i][c1 + j] = cur[i * 3 + j];
    LDS_BARRIER();

#pragma unroll 1
    for (int s = 1; s <= KSTEPS; ++s) {
        const v2f (*rb)[SCOL] = sb[(s - 1) & 1];
        v2f (*wb)[SCOL] = sb[s & 1];
        const float sig_t = sig[t0 + s - 1];

        // halo reads: all static offsets (pad ring = zero boundary)
        v2f T[5], Bo[5], Lc[3], Rc[3];
#pragma unroll
        for (int j = 0; j < 5; ++j) {
            T[j]  = rb[r1 - 1][c1 - 1 + j];   // contiguous -> ds_read2_b64
            Bo[j] = rb[r1 + 3][c1 - 1 + j];
        }
#pragma unroll
        for (int i = 0; i < 3; ++i) {
            Lc[i] = rb[r1 + i][c1 - 1];       // stride SCOL -> ds_read2_b64
            Rc[i] = rb[r1 + i][c1 + 3];
        }

        // assemble 5x5 v2f window
        v2f v[5][5];
#pragma unroll
        for (int j = 0; j < 5; ++j) { v[0][j] = T[j]; v[4][j] = Bo[j]; }
#pragma unroll
        for (int i = 0; i < 3; ++i) {
            v[i + 1][0] = Lc[i];
            v[i + 1][4] = Rc[i];
#pragma unroll
            for (int j = 0; j < 3; ++j)
                v[i + 1][j + 1] = cur[i * 3 + j];
        }

        // horizontal differences shared across the 9 points' cross-derivs
        v2f dh[5][3];
#pragma unroll
        for (int i = 0; i < 5; ++i)
#pragma unroll
            for (int j = 0; j < 3; ++j)
                dh[i][j] = v[i][j + 2] - v[i][j];

        const v2f m2 = vbc(-2.0f);
        const v2f qt = vbc(0.25f);
#pragma unroll
        for (int i = 0; i < 3; ++i)
#pragma unroll
            for (int j = 0; j < 3; ++j) {
                int p = i * 3 + j;
                v2f c = v[i + 1][j + 1];
                v2f sxx = vfma(m2, c, v[i][j + 1] + v[i + 2][j + 1]);  // pk
                v2f syy = vfma(m2, c, v[i + 1][j] + v[i + 1][j + 2]);  // pk
                v2f sxy = qt * (dh[i + 2][j] - dh[i][j]);              // pk

                float lux = fmaf(a11[p], sxx[0],
                            fmaf(a66[p], syy[0],
                            fmaf(a12p66[p], sxy[1],
                            fmaf(a16[p], fmaf(2.0f, sxy[0], sxx[1]),
                                 a26[p] * syy[1]))));
                float luy = fmaf(a66[p], sxx[1],
                            fmaf(a22[p], syy[1],
                            fmaf(a12p66[p], sxy[0],
                            fmaf(a16[p], sxx[0],
                                 a26[p] * fmaf(2.0f, sxy[1], syy[0])))));

                float nx = fmaf(2.0f, c[0], lux) - old_[p][0];
                float ny = fmaf(2.0f, c[1], fmaf(sig_t, gs[p], luy)) - old_[p][1];
                old_[p] = c;
                v2f n; n[0] = nx; n[1] = ny;
                cur[p] = n;
            }

        // frame output at global t = t0 + s - 1; t%4==3 <=> s%4==0
        // (stores are fire-and-forget: barrier below does NOT drain vmcnt)
        if ((s & 3) == 0 && owned) {
            int f = 3 * L + (s >> 2) - 1;
            float* oux = out + (size_t)f * NPT;
            float* ouy = out + (size_t)(NFRAMES + f) * NPT;
#pragma unroll
            for (int p = 0; p < 9; ++p) {
                oux[gidx[p]] = cur[p][0];
                ouy[gidx[p]] = cur[p][1];
            }
        }

        // publish new values (contiguous rows -> ds_write2_b64 merging)
#pragma unroll
        for (int i = 0; i < 3; ++i)
#pragma unroll
            for (int j = 0; j < 3; ++j)
                wb[r1 + i][c1 + j] = cur[i * 3 + j];
        LDS_BARRIER();
    }

    if (owned) {
#pragma unroll
        for (int p = 0; p < 9; ++p) {
            int g = gidx[p];
            outCur[g] = cur[p];
            outOld[g] = old_[p];
        }
    }
}

extern "C" void kernel_launch(void* const* d_in, const int* in_sizes, int n_in,
                              void* d_out, int out_size, void* d_ws, size_t ws_size,
                              hipStream_t stream) {
    const float* lc11  = (const float*)d_in[0];
    const float* lc12  = (const float*)d_in[1];
    const float* lc16  = (const float*)d_in[2];
    const float* lc22  = (const float*)d_in[3];
    const float* lc26  = (const float*)d_in[4];
    const float* lc66  = (const float*)d_in[5];
    const float* gauss = (const float*)d_in[6];
    const float* sig   = (const float*)d_in[7];

    float* ws  = (float*)d_ws;
    float* out = (float*)d_out;

    setup_kernel<<<(NPT + 255) / 256, 256, 0, stream>>>(lc11, lc12, lc16, lc22,
                                                        lc26, lc66, gauss, ws);

    v2f* set0c = (v2f*)(ws + 7 * (size_t)NPT);
    v2f* set0o = set0c + NPT;
    v2f* set1c = (v2f*)(ws + 11 * (size_t)NPT);
    v2f* set1o = set1c + NPT;

    dim3 grid(NXg / OWN, NYg / OWN);  // 16x16 = 256 blocks, 1 per CU
    for (int L = 0; L < NLAUNCH; ++L) {
        v2f* ic = (L & 1) ? set1c : set0c;
        v2f* io = (L & 1) ? set1o : set0o;
        v2f* oc = (L & 1) ? set0c : set1c;
        v2f* oo = (L & 1) ? set0o : set1o;
        fused_kernel<<<grid, 256, 0, stream>>>(ws, sig, ic, io, oc, oo, out, L);
    }
}

// Round 9
// 353.743 us; speedup vs baseline: 1.0687x; 1.0687x over previous
//
#include <hip/hip_runtime.h>

// Spatially varying anisotropic 2D elastic wave sim, 384x384, 192 steps.
// Round 8: R6 geometry (256 blocks=1/CU, 256 thr, 48x48 staging, K=12,
// 16 launches, packed v2f LDS + pk stencil math), plus:
//  - WIDE prologue/epilogue: coeffs pre-packed as two float4 planes,
//    state as one float4 {cur.x,cur.y,old.x,old.y} -> dwordx4 traffic
//    (was ~99 scalar loads + 18 scalar stores per thread per launch)
//  - sig[] preloaded into registers once per launch (no s_loads in loop)
//  - lgkm-only barrier (frame stores never drain at the step barrier)
//  - packed v2f lux/luy chain (exact-preserving {2,0}/{0,sig} constants)

typedef float v2f __attribute__((ext_vector_type(2)));

#define NXg 384
#define NYg 384
#define NPT (NXg * NYg)
#define NFRAMES 48

#define OWN 24
#define HALO 12
#define TS 48
#define KSTEPS 12
#define NLAUNCH 16

#define H_   1e-4
#define DT_  5e-9
#define RHO_ 1610.0

#define B11_LO 5e10f
#define B11_HI 2.5e11f
#define B22_LO 5e9f
#define B22_HI 5e10f
#define B12_LO 5e9f
#define B12_HI 5e10f
#define B16_LO 0.0f
#define B16_HI 6e10f
#define B26_LO 0.0f
#define B26_HI 2e10f
#define B66_LO 5e9f
#define B66_HI 3e10f

static __device__ __constant__ float kScale  = (float)(DT_ * DT_ / (H_ * H_) / RHO_);
static __device__ __constant__ float kSrcScl = (float)(DT_ * DT_ / RHO_);

__device__ __forceinline__ float clipf(float v, float lo, float hi) {
    return fminf(fmaxf(v, lo), hi);
}
__device__ __forceinline__ v2f vfma(v2f a, v2f b, v2f c) {
    return __builtin_elementwise_fma(a, b, c);
}
__device__ __forceinline__ v2f vbc(float s) { v2f r; r[0] = s; r[1] = s; return r; }
__device__ __forceinline__ v2f vswap(v2f a) { return __builtin_shufflevector(a, a, 1, 0); }

// barrier that only waits LDS (no vmcnt drain); memory clobber pins ordering
#define LDS_BARRIER() asm volatile("s_waitcnt lgkmcnt(0)\n\ts_barrier" ::: "memory")

// ws float layout:
// [0..4NPT):   C0 = float4{A11, A22, A12p66, A16}  (pre-scaled)
// [4NPT..8NPT):C1 = float4{A26, A66, GS, 0}
// [8NPT..12NPT):  state set0: float4{cur.x, cur.y, old.x, old.y}
// [12NPT..16NPT): state set1

__global__ __launch_bounds__(256)
void setup_kernel(const float* __restrict__ lc11, const float* __restrict__ lc12,
                  const float* __restrict__ lc16, const float* __restrict__ lc22,
                  const float* __restrict__ lc26, const float* __restrict__ lc66,
                  const float* __restrict__ gauss, float* __restrict__ ws) {
    int i = blockIdx.x * blockDim.x + threadIdx.x;
    if (i >= NPT) return;
    float C11 = clipf(expf(lc11[i]), B11_LO, B11_HI);
    float C12 = clipf(expf(lc12[i]), B12_LO, B12_HI);
    float C16 = clipf(expf(lc16[i]), B16_LO, B16_HI);
    float C22 = clipf(expf(lc22[i]), B22_LO, B22_HI);
    float C26 = clipf(expf(lc26[i]), B26_LO, B26_HI);
    float C66 = clipf(expf(lc66[i]), B66_LO, B66_HI);
    float s = kScale;
    float4* C0 = (float4*)ws;
    float4* C1 = (float4*)(ws + 4 * (size_t)NPT);
    C0[i] = make_float4(C11 * s, C22 * s, (C12 + C66) * s, C16 * s);
    C1[i] = make_float4(C26 * s, C66 * s, gauss[i] * kSrcScl, 0.0f);
    float4* s0 = (float4*)(ws + 8 * (size_t)NPT);
    s0[i] = make_float4(0.0f, 0.0f, 0.0f, 0.0f);
}

__global__ __launch_bounds__(256, 1)
void fused_kernel(const float* __restrict__ ws, const float* __restrict__ sig,
                  const float4* __restrict__ inS, float4* __restrict__ outS,
                  float* __restrict__ out, int L) {
    __shared__ v2f sb[2][TS][TS + 1];

    const int tid = threadIdx.x;
    const int tx = tid >> 4;
    const int ty = tid & 15;
    const int r0 = 3 * tx;
    const int c0 = 3 * ty;
    const int gx0 = blockIdx.y * OWN - HALO;
    const int gy0 = blockIdx.x * OWN - HALO;

    const float4* __restrict__ C0 = (const float4*)ws;
    const float4* __restrict__ C1 = (const float4*)(ws + 4 * (size_t)NPT);

    v2f cur[9], old_[9];
    v2f ca[9], cb[9];                       // {A11,A66}, {A66,A22}
    float a12p66[9], a16[9], a26[9], gs[9];
    int gidx[9];

#pragma unroll
    for (int i = 0; i < 3; ++i) {
#pragma unroll
        for (int j = 0; j < 3; ++j) {
            int p = i * 3 + j;
            int gx = gx0 + r0 + i;
            int gy = gy0 + c0 + j;
            bool d = (unsigned)gx < (unsigned)NXg && (unsigned)gy < (unsigned)NYg;
            int g = d ? gx * NYg + gy : 0;
            gidx[p] = g;
            float4 st = d ? inS[g] : make_float4(0, 0, 0, 0);
            v2f c; c[0] = st.x; c[1] = st.y;
            v2f o; o[0] = st.z; o[1] = st.w;
            cur[p] = c; old_[p] = o;
            float4 k0 = d ? C0[g] : make_float4(0, 0, 0, 0);
            float4 k1 = d ? C1[g] : make_float4(0, 0, 0, 0);
            v2f t; t[0] = k0.x; t[1] = k1.y; ca[p] = t;   // {A11, A66}
            v2f u; u[0] = k1.y; u[1] = k0.y; cb[p] = u;   // {A66, A22}
            a12p66[p] = k0.z; a16[p] = k0.w; a26[p] = k1.x; gs[p] = k1.z;
        }
    }

    // preload all step source values (no s_loads inside the loop)
    const int t0 = L * KSTEPS;
    float sigv[KSTEPS];
#pragma unroll
    for (int k = 0; k < KSTEPS; ++k) sigv[k] = sig[t0 + k];

    // clamped halo coords (trapezoid garbage-tolerance at staging rim)
    const int rm = (r0 > 0) ? r0 - 1 : 0;
    const int rp = (r0 + 3 < TS) ? r0 + 3 : TS - 1;
    const int cm = (c0 > 0) ? c0 - 1 : 0;
    const int cp = (c0 + 3 < TS) ? c0 + 3 : TS - 1;

    const bool owned = (tx >= 4) && (tx < 12) && (ty >= 4) && (ty < 12);

    // publish initial values into buffer 0
#pragma unroll
    for (int i = 0; i < 3; ++i)
#pragma unroll
        for (int j = 0; j < 3; ++j)
            sb[0][r0 + i][c0 + j] = cur[i * 3 + j];
    LDS_BARRIER();

    v2f c20; c20[0] = 2.0f; c20[1] = 0.0f;
    v2f c02; c02[0] = 0.0f; c02[1] = 2.0f;
    const v2f m2 = vbc(-2.0f);
    const v2f qt = vbc(0.25f);
    const v2f two = vbc(2.0f);

#pragma unroll 1
    for (int s = 1; s <= KSTEPS; ++s) {
        const v2f (*rb)[TS + 1] = sb[(s - 1) & 1];
        v2f (*wb)[TS + 1] = sb[s & 1];
        v2f vsig; vsig[0] = 0.0f; vsig[1] = sigv[s - 1];

        // assemble 5x5 v2f window: own 3x3 from regs + 16 halo b64 reads
        v2f v[5][5];
#pragma unroll
        for (int i = 0; i < 3; ++i)
#pragma unroll
            for (int j = 0; j < 3; ++j)
                v[i + 1][j + 1] = cur[i * 3 + j];
        v[0][0] = rb[rm][cm];  v[0][4] = rb[rm][cp];
        v[4][0] = rb[rp][cm];  v[4][4] = rb[rp][cp];
#pragma unroll
        for (int j = 0; j < 3; ++j) {
            v[0][j + 1] = rb[rm][c0 + j];
            v[4][j + 1] = rb[rp][c0 + j];
            v[j + 1][0] = rb[r0 + j][cm];
            v[j + 1][4] = rb[r0 + j][cp];
        }

        // horizontal differences shared across the 9 points' cross-derivs
        v2f dh[5][3];
#pragma unroll
        for (int i = 0; i < 5; ++i)
#pragma unroll
            for (int j = 0; j < 3; ++j)
                dh[i][j] = v[i][j + 2] - v[i][j];

#pragma unroll
        for (int i = 0; i < 3; ++i)
#pragma unroll
            for (int j = 0; j < 3; ++j) {
                int p = i * 3 + j;
                v2f c = v[i + 1][j + 1];
                v2f sxx = vfma(m2, c, v[i][j + 1] + v[i + 2][j + 1]);  // pk
                v2f syy = vfma(m2, c, v[i + 1][j] + v[i + 1][j + 2]);  // pk
                v2f sxy = qt * (dh[i + 2][j] - dh[i][j]);              // pk

                // t4 = {2*sxy.x + sxx.y, sxx.x}; t5 = {syy.y, 2*sxy.y + syy.x}
                v2f t4 = vfma(c20, vbc(sxy[0]), vswap(sxx));
                v2f t5 = vfma(c02, vbc(sxy[1]), vswap(syy));
                // L = {lux, luy}
                v2f Lv = ca[p] * sxx;
                Lv = vfma(cb[p], syy, Lv);
                Lv = vfma(vbc(a12p66[p]), vswap(sxy), Lv);
                Lv = vfma(vbc(a16[p]), t4, Lv);
                Lv = vfma(vbc(a26[p]), t5, Lv);
                // source on y only: {lux, sig*gs + luy} (exact: 0*gs+lux)
                Lv = vfma(vsig, vbc(gs[p]), Lv);
                // n = fma(2, c, L) - old
                v2f n = vfma(two, c, Lv) - old_[p];
                old_[p] = c;
                cur[p] = n;
            }

        // frame output at global t = t0 + s - 1; t%4==3 <=> s%4==0
        // (fire-and-forget: the step barrier does NOT drain vmcnt)
        if ((s & 3) == 0 && owned) {
            int f = 3 * L + (s >> 2) - 1;
            float* oux = out + (size_t)f * NPT;
            float* ouy = out + (size_t)(NFRAMES + f) * NPT;
#pragma unroll
            for (int p = 0; p < 9; ++p) {
                oux[gidx[p]] = cur[p][0];
                ouy[gidx[p]] = cur[p][1];
            }
        }

        // publish new values; ONE lgkm-only barrier per step (double buffered)
#pragma unroll
        for (int i = 0; i < 3; ++i)
#pragma unroll
            for (int j = 0; j < 3; ++j)
                wb[r0 + i][c0 + j] = cur[i * 3 + j];
        LDS_BARRIER();
    }

    if (owned) {
#pragma unroll
        for (int p = 0; p < 9; ++p) {
            float4 st = make_float4(cur[p][0], cur[p][1], old_[p][0], old_[p][1]);
            outS[gidx[p]] = st;
        }
    }
}

extern "C" void kernel_launch(void* const* d_in, const int* in_sizes, int n_in,
                              void* d_out, int out_size, void* d_ws, size_t ws_size,
                              hipStream_t stream) {
    const float* lc11  = (const float*)d_in[0];
    const float* lc12  = (const float*)d_in[1];
    const float* lc16  = (const float*)d_in[2];
    const float* lc22  = (const float*)d_in[3];
    const float* lc26  = (const float*)d_in[4];
    const float* lc66  = (const float*)d_in[5];
    const float* gauss = (const float*)d_in[6];
    const float* sig   = (const float*)d_in[7];

    float* ws  = (float*)d_ws;
    float* out = (float*)d_out;

    setup_kernel<<<(NPT + 255) / 256, 256, 0, stream>>>(lc11, lc12, lc16, lc22,
                                                        lc26, lc66, gauss, ws);

    float4* set0 = (float4*)(ws + 8 * (size_t)NPT);
    float4* set1 = (float4*)(ws + 12 * (size_t)NPT);

    dim3 grid(NXg / OWN, NYg / OWN);  // 16x16 = 256 blocks, 1 per CU
    for (int L = 0; L < NLAUNCH; ++L) {
        float4* iS = (L & 1) ? set1 : set0;
        float4* oS = (L & 1) ? set0 : set1;
        fused_kernel<<<grid, 256, 0, stream>>>(ws, sig, iS, oS, out, L);
    }
}